// Round 1
// baseline (826.739 us; speedup 1.0000x reference)
//
#include <hip/hip_runtime.h>
#include <stdint.h>

#define DEVI __device__ __forceinline__

typedef unsigned short u16;
typedef __attribute__((ext_vector_type(8))) __bf16 bf16x8;   // 4 VGPRs, MFMA A/B frag
typedef __attribute__((ext_vector_type(4))) float f32x4;     // MFMA C/D frag

// ---- bf16 <-> f32 (RNE, matches numpy-side rounding closely enough) ----
DEVI float b2f(u16 u) { union { unsigned int i; float f; } v; v.i = ((unsigned int)u) << 16; return v.f; }
DEVI u16 f2b(float f) {
  union { float f; unsigned int i; } v; v.f = f;
  unsigned int r = v.i + 0x7fffu + ((v.i >> 16) & 1u);
  return (u16)(r >> 16);
}

// ---- async global->LDS, 16B per lane (wave-uniform base + lane*16) ----
DEVI void gld_lds16(const u16* g, u16* l) {
  __builtin_amdgcn_global_load_lds((const __attribute__((address_space(1))) unsigned int*)g,
                                   (__attribute__((address_space(3))) unsigned int*)l, 16, 0, 0);
}

// =======================================================================
// Elementwise / prep kernels
// =======================================================================

// one block per row of 1024; thread t owns 4 floats
__global__ __launch_bounds__(256) void k_rmsnorm(const float* __restrict__ x,
                                                 const float* __restrict__ g,
                                                 u16* __restrict__ h) {
  const int row = blockIdx.x;
  const int t = threadIdx.x;
  const float4 v = ((const float4*)(x + (size_t)row * 1024))[t];
  float ss = v.x * v.x + v.y * v.y + v.z * v.z + v.w * v.w;
  for (int off = 32; off > 0; off >>= 1) ss += __shfl_down(ss, off);
  __shared__ float red[4];
  if ((t & 63) == 0) red[t >> 6] = ss;
  __syncthreads();
  const float tot = red[0] + red[1] + red[2] + red[3];
  const float sc = rsqrtf(tot * (1.0f / 1024.0f) + 1e-6f);
  const float4 gv = ((const float4*)g)[t];
  ushort4 o;
  o.x = f2b(v.x * sc * gv.x); o.y = f2b(v.y * sc * gv.y);
  o.z = f2b(v.z * sc * gv.z); o.w = f2b(v.w * sc * gv.w);
  *(ushort4*)(h + (size_t)row * 1024 + t * 4) = o;
}

// dst[c][r] = (bf16) src[r][c]   (weights -> N x K layout for the GEMM B-operand)
__global__ __launch_bounds__(256) void k_transpose_cast(const float* __restrict__ src,
                                                        int rows, int cols,
                                                        u16* __restrict__ dst) {
  __shared__ float tile[32][33];
  const int c0 = blockIdx.x * 32, r0 = blockIdx.y * 32;
  const int tx = threadIdx.x, ty = threadIdx.y;
  for (int i = 0; i < 32; i += 8)
    tile[ty + i][tx] = src[(size_t)(r0 + ty + i) * cols + c0 + tx];
  __syncthreads();
  for (int i = 0; i < 32; i += 8)
    dst[(size_t)(c0 + ty + i) * rows + r0 + tx] = f2b(tile[tx][ty + i]);
}

// vt[b][d][s] = qkv[b*4096+s][2048+d]   (V^T per batch, bf16->bf16)
__global__ __launch_bounds__(256) void k_vt(const u16* __restrict__ qkv, u16* __restrict__ vt) {
  __shared__ u16 tile[32][33];
  const int b = blockIdx.z;
  const int s0 = blockIdx.x * 32, d0 = blockIdx.y * 32;
  const int tx = threadIdx.x, ty = threadIdx.y;
  for (int i = 0; i < 32; i += 8)
    tile[ty + i][tx] = qkv[(size_t)(b * 4096 + s0 + ty + i) * 3072 + 2048 + d0 + tx];
  __syncthreads();
  for (int i = 0; i < 32; i += 8)
    vt[(size_t)(b * 1024 + d0 + ty + i) * 4096 + s0 + tx] = tile[tx][ty + i];
}

// in-place ternary rope on q (cols 0..1023) and k (cols 1024..2047) of qkv
// out[j]     = t[j]*c - t[j+512]*s ;  out[j+512] = t[j+512]*c + t[j]*s
// c,s = rintf(cos/sin(pos * 10000^{-j/512}))  -- rintf == numpy round-half-even
__global__ __launch_bounds__(256) void k_rope(u16* __restrict__ qkv) {
  const int row = blockIdx.x;
  const float pos = (float)(row & 4095);
  u16* base = qkv + (size_t)row * 3072;
  const int j = threadIdx.x * 2;
  float c[2], sn[2];
#pragma unroll
  for (int u = 0; u < 2; u++) {
    float e = (float)(j + u) * (1.0f / 512.0f);
    float invf = 1.0f / powf(10000.0f, e);
    float ang = pos * invf;
    c[u] = rintf(cosf(ang));
    sn[u] = rintf(sinf(ang));
  }
#pragma unroll
  for (int m = 0; m < 2; m++) {
    u16* p0 = base + m * 1024 + j;
    u16* p1 = p0 + 512;
    ushort2 a = *(ushort2*)p0, bq = *(ushort2*)p1;
    float a0 = b2f(a.x), a1 = b2f(a.y), b0 = b2f(bq.x), b1 = b2f(bq.y);
    ushort2 na, nb;
    na.x = f2b(a0 * c[0] - b0 * sn[0]);
    na.y = f2b(a1 * c[1] - b1 * sn[1]);
    nb.x = f2b(b0 * c[0] + a0 * sn[0]);
    nb.y = f2b(b1 * c[1] + a1 * sn[1]);
    *(ushort2*)p0 = na;
    *(ushort2*)p1 = nb;
  }
}

// =======================================================================
// Shared MFMA GEMM core: C[128x128] += A[M x K](lda) * Bt[N x K](ldb)^T
// block = 256 threads (4 waves, 2x2), wave = 64x64 = 4x4 MFMA 16x16x32 tiles
// m97 structure: global_load_lds(16B) staging, 2-barrier K-loop, BK=32
// =======================================================================
DEVI void gemm_tile(const u16* __restrict__ A, int lda,
                    const u16* __restrict__ B, int ldb,
                    int K, int m0, int n0,
                    u16* As, u16* Bs, f32x4 acc[4][4]) {
  const int t = threadIdx.x;
  const int sr = t >> 2;              // staging row within 64-row group
  const int sc = (t & 3) * 8;         // staging k-offset (elements)
  const u16* Ag0 = A + (size_t)(m0 + sr) * lda + sc;
  const u16* Ag1 = A + (size_t)(m0 + 64 + sr) * lda + sc;
  const u16* Bg0 = B + (size_t)(n0 + sr) * ldb + sc;
  const u16* Bg1 = B + (size_t)(n0 + 64 + sr) * ldb + sc;
  u16* Asw0 = As + t * 8;             // lane-ordered: wave base + lane*16B
  u16* Asw1 = As + 2048 + t * 8;
  u16* Bsw0 = Bs + t * 8;
  u16* Bsw1 = Bs + 2048 + t * 8;

  const int lane = t & 63, qd = lane >> 4, l16 = lane & 15;
  const int wave = t >> 6;
  const int wm = (wave >> 1) * 64, wn = (wave & 1) * 64;
  const u16* Ard = As + (size_t)(wm + l16) * 32 + qd * 8;  // A-frag: m=lane&15, k=quad*8+j
  const u16* Brd = Bs + (size_t)(wn + l16) * 32 + qd * 8;  // B-frag: n=lane&15, k=quad*8+j

  for (int k0 = 0; k0 < K; k0 += 32) {
    gld_lds16(Ag0 + k0, Asw0);
    gld_lds16(Ag1 + k0, Asw1);
    gld_lds16(Bg0 + k0, Bsw0);
    gld_lds16(Bg1 + k0, Bsw1);
    __builtin_amdgcn_s_waitcnt(0);    // drain vmcnt before barrier (defensive)
    __syncthreads();
    bf16x8 af[4], bfv[4];
#pragma unroll
    for (int i = 0; i < 4; i++) af[i] = *(const bf16x8*)(Ard + i * 16 * 32);
#pragma unroll
    for (int j = 0; j < 4; j++) bfv[j] = *(const bf16x8*)(Brd + j * 16 * 32);
#pragma unroll
    for (int i = 0; i < 4; i++)
#pragma unroll
      for (int j = 0; j < 4; j++)
        acc[i][j] = __builtin_amdgcn_mfma_f32_16x16x32_bf16(af[i], bfv[j], acc[i][j], 0, 0, 0);
    __syncthreads();
  }
}

#define GEMM_PROLOGUE()                                          \
  __shared__ alignas(16) u16 As[4096], Bs[4096];                 \
  f32x4 acc[4][4];                                               \
  _Pragma("unroll") for (int i = 0; i < 4; i++)                  \
      _Pragma("unroll") for (int j = 0; j < 4; j++)              \
          acc[i][j] = f32x4{0.f, 0.f, 0.f, 0.f};

#define GEMM_EPI_IDX()                                           \
  const int t = threadIdx.x, lane = t & 63, qd = lane >> 4,      \
            l16 = lane & 15, wave = t >> 6;                      \
  const int wm = (wave >> 1) * 64, wn = (wave & 1) * 64;         \
  (void)t;

// C/D layout (verified m89/m91): col = lane&15, row = quad*4 + reg

// qkv = h @ WqkvT^T + bias  -> bf16 [16384][3072]
__global__ __launch_bounds__(256) void k_gemm_qkv(const u16* __restrict__ A, const u16* __restrict__ Bt,
                                                  const float* __restrict__ bias, u16* __restrict__ C) {
  GEMM_PROLOGUE();
  const int m0 = blockIdx.y * 128, n0 = blockIdx.x * 128;
  gemm_tile(A, 1024, Bt, 1024, 1024, m0, n0, As, Bs, acc);
  GEMM_EPI_IDX();
#pragma unroll
  for (int i = 0; i < 4; i++) {
    const int mb = m0 + wm + i * 16 + qd * 4;
#pragma unroll
    for (int j = 0; j < 4; j++) {
      const int col = n0 + wn + j * 16 + l16;
      const float bv = bias[col];
#pragma unroll
      for (int r = 0; r < 4; r++)
        C[(size_t)(mb + r) * 3072 + col] = f2b(acc[i][j][r] + bv);
    }
  }
}

// P = 3^(q k^T / 32) bf16, plus row sums ls (atomic partial adds)
__global__ __launch_bounds__(256) void k_gemm_scores(const u16* __restrict__ qkv, u16* __restrict__ P,
                                                     float* __restrict__ ls, int b0) {
  GEMM_PROLOGUE();
  const int zz = blockIdx.z, b = b0 + zz;
  const u16* A = qkv + (size_t)b * 4096 * 3072;  // q rows of this batch
  const u16* Bt = A + 1024;                      // k rows (col offset 1024)
  const int m0 = blockIdx.y * 128, n0 = blockIdx.x * 128;
  gemm_tile(A, 3072, Bt, 3072, 1024, m0, n0, As, Bs, acc);
  GEMM_EPI_IDX();
  const float C3 = 0.04953007814753613f;  // log2(3) / 32
  const size_t Pb = (size_t)zz * 4096 * 4096;
  f32x4 rowp[4];
#pragma unroll
  for (int i = 0; i < 4; i++) rowp[i] = f32x4{0.f, 0.f, 0.f, 0.f};
#pragma unroll
  for (int i = 0; i < 4; i++) {
    const int mb = m0 + wm + i * 16 + qd * 4;
#pragma unroll
    for (int j = 0; j < 4; j++) {
      const int col = n0 + wn + j * 16 + l16;
#pragma unroll
      for (int r = 0; r < 4; r++) {
        float pv = exp2f(acc[i][j][r] * C3);
        u16 pq = f2b(pv);
        P[Pb + (size_t)(mb + r) * 4096 + col] = pq;
        rowp[i][r] += b2f(pq);  // sum the quantized value: numerator/denominator consistent
      }
    }
  }
  // reduce over the 16 lanes sharing a row-quad (xor masks stay inside the 16-group)
#pragma unroll
  for (int m = 1; m < 16; m <<= 1)
#pragma unroll
    for (int i = 0; i < 4; i++) {
      rowp[i].x += __shfl_xor(rowp[i].x, m);
      rowp[i].y += __shfl_xor(rowp[i].y, m);
      rowp[i].z += __shfl_xor(rowp[i].z, m);
      rowp[i].w += __shfl_xor(rowp[i].w, m);
    }
  if (l16 == 0) {
#pragma unroll
    for (int i = 0; i < 4; i++) {
      const int mb = m0 + wm + i * 16 + qd * 4;
#pragma unroll
      for (int r = 0; r < 4; r++)
        atomicAdd(ls + (size_t)b * 4096 + mb + r, rowp[i][r]);
    }
  }
}

// o = (P @ V) / ls   -> bf16 [b*4096+s][1024]
__global__ __launch_bounds__(256) void k_gemm_pv(const u16* __restrict__ P, const u16* __restrict__ vt,
                                                 const float* __restrict__ ls, u16* __restrict__ o, int b0) {
  GEMM_PROLOGUE();
  const int zz = blockIdx.z, b = b0 + zz;
  const u16* A = P + (size_t)zz * 4096 * 4096;
  const u16* Bt = vt + (size_t)b * 1024 * 4096;
  const int m0 = blockIdx.y * 128, n0 = blockIdx.x * 128;
  gemm_tile(A, 4096, Bt, 4096, 4096, m0, n0, As, Bs, acc);
  GEMM_EPI_IDX();
#pragma unroll
  for (int i = 0; i < 4; i++) {
    const int mb = m0 + wm + i * 16 + qd * 4;
    f32x4 inv;
#pragma unroll
    for (int r = 0; r < 4; r++) inv[r] = 1.0f / ls[(size_t)b * 4096 + mb + r];
#pragma unroll
    for (int j = 0; j < 4; j++) {
      const int col = n0 + wn + j * 16 + l16;
#pragma unroll
      for (int r = 0; r < 4; r++)
        o[(size_t)(b * 4096 + mb + r) * 1024 + col] = f2b(acc[i][j][r] * inv[r]);
    }
  }
}

// out = o @ WprojT^T + bias + x   (fp32 output)
__global__ __launch_bounds__(256) void k_gemm_proj(const u16* __restrict__ A, const u16* __restrict__ Bt,
                                                   const float* __restrict__ bias, const float* __restrict__ x,
                                                   float* __restrict__ out) {
  GEMM_PROLOGUE();
  const int m0 = blockIdx.y * 128, n0 = blockIdx.x * 128;
  gemm_tile(A, 1024, Bt, 1024, 1024, m0, n0, As, Bs, acc);
  GEMM_EPI_IDX();
#pragma unroll
  for (int i = 0; i < 4; i++) {
    const int mb = m0 + wm + i * 16 + qd * 4;
#pragma unroll
    for (int j = 0; j < 4; j++) {
      const int col = n0 + wn + j * 16 + l16;
      const float bv = bias[col];
#pragma unroll
      for (int r = 0; r < 4; r++) {
        const size_t idx = (size_t)(mb + r) * 1024 + col;
        out[idx] = acc[i][j][r] + bv + x[idx];
      }
    }
  }
}

// =======================================================================
extern "C" void kernel_launch(void* const* d_in, const int* in_sizes, int n_in,
                              void* d_out, int out_size, void* d_ws, size_t ws_size,
                              hipStream_t stream) {
  const float* x     = (const float*)d_in[0];
  const float* g     = (const float*)d_in[1];
  const float* wqkv  = (const float*)d_in[2];
  const float* bqkv  = (const float*)d_in[3];
  const float* wproj = (const float*)d_in[4];
  const float* bproj = (const float*)d_in[5];
  float* out = (float*)d_out;

  char* wsp = (char*)d_ws;
  size_t off = 0;
  auto take = [&](size_t bytes) -> void* {
    off = (off + 255) & ~(size_t)255;
    void* r = wsp + off;
    off += bytes;
    return r;
  };
  u16* h    = (u16*)take(16384ull * 1024 * 2);   // rmsnorm out; reused as o (PV out)
  u16* wqT  = (u16*)take(3072ull * 1024 * 2);
  u16* wpT  = (u16*)take(1024ull * 1024 * 2);
  u16* qkv  = (u16*)take(16384ull * 3072 * 2);
  u16* vt   = (u16*)take(4ull * 1024 * 4096 * 2);
  float* ls = (float*)take(16384ull * 4);
  off = (off + 255) & ~(size_t)255;
  // P chunk: as many batches as the workspace allows (ws_size is call-invariant)
  int nb = 4;
  while (nb > 1 && off + (size_t)nb * 4096 * 4096 * 2 > ws_size) nb >>= 1;
  u16* P = (u16*)(wsp + off);

  k_transpose_cast<<<dim3(3072 / 32, 1024 / 32), dim3(32, 8), 0, stream>>>(wqkv, 1024, 3072, wqT);
  k_transpose_cast<<<dim3(1024 / 32, 1024 / 32), dim3(32, 8), 0, stream>>>(wproj, 1024, 1024, wpT);
  k_rmsnorm<<<16384, 256, 0, stream>>>(x, g, h);
  k_gemm_qkv<<<dim3(24, 128), 256, 0, stream>>>(h, wqT, bqkv, qkv);
  k_rope<<<16384, 256, 0, stream>>>(qkv);
  k_vt<<<dim3(128, 32, 4), dim3(32, 8), 0, stream>>>(qkv, vt);
  hipMemsetAsync(ls, 0, 16384 * 4, stream);
  for (int b0 = 0; b0 < 4; b0 += nb) {
    k_gemm_scores<<<dim3(32, 32, nb), 256, 0, stream>>>(qkv, P, ls, b0);
    k_gemm_pv<<<dim3(8, 32, nb), 256, 0, stream>>>(P, vt, ls, h /*=o*/, b0);
  }
  k_gemm_proj<<<dim3(8, 128), 256, 0, stream>>>(h /*=o*/, wpT, bproj, x, out);
}

// Round 2
// 752.841 us; speedup vs baseline: 1.0982x; 1.0982x over previous
//
#include <hip/hip_runtime.h>
#include <stdint.h>

#define DEVI __device__ __forceinline__

typedef unsigned short u16;
typedef __attribute__((ext_vector_type(8))) __bf16 bf16x8;   // 4 VGPRs, MFMA A/B frag
typedef __attribute__((ext_vector_type(4))) float f32x4;     // MFMA C/D frag

DEVI float b2f(u16 u) { union { unsigned int i; float f; } v; v.i = ((unsigned int)u) << 16; return v.f; }
DEVI u16 f2b(float f) {
  union { float f; unsigned int i; } v; v.f = f;
  unsigned int r = v.i + 0x7fffu + ((v.i >> 16) & 1u);
  return (u16)(r >> 16);
}

DEVI void gld_lds16(const u16* g, u16* l) {
  __builtin_amdgcn_global_load_lds((const __attribute__((address_space(1))) unsigned int*)g,
                                   (__attribute__((address_space(3))) unsigned int*)l, 16, 0, 0);
}

// qkv staging-row permutation: within q/k sections, permuted row 2p -> p, 2p+1 -> p+512
// so rope pairs (p, p+512) land in adjacent epilogue lanes. v section identity.
DEVI int qkv_permrow(int r) {
  const int sec = r >> 10, w = r & 1023;
  const int pw = (sec < 2) ? (((w & 1) ? 512 : 0) + (w >> 1)) : w;
  return (sec << 10) | pw;
}

// =======================================================================
// Elementwise / prep kernels
// =======================================================================

// ternary cos/sin table: cs[pos*512+p] = packed(int8 c, int8 s). Same fp32 math
// as the passing R1 k_rope (powf/cosf/sinf/rintf).
__global__ __launch_bounds__(256) void k_cs_table(short* __restrict__ cs) {
  const int idx = blockIdx.x * 256 + threadIdx.x;   // 4096*512 entries
  const int pos = idx >> 9, p = idx & 511;
  const float e = (float)p * (1.0f / 512.0f);
  const float invf = 1.0f / powf(10000.0f, e);
  const float ang = (float)pos * invf;
  const signed char c8 = (signed char)rintf(cosf(ang));
  const signed char s8 = (signed char)rintf(sinf(ang));
  cs[idx] = (short)((unsigned char)c8 | ((unsigned short)(unsigned char)s8 << 8));
}

__global__ __launch_bounds__(256) void k_rmsnorm(const float* __restrict__ x,
                                                 const float* __restrict__ g,
                                                 u16* __restrict__ h) {
  const int row = blockIdx.x;
  const int t = threadIdx.x;
  const float4 v = ((const float4*)(x + (size_t)row * 1024))[t];
  float ss = v.x * v.x + v.y * v.y + v.z * v.z + v.w * v.w;
  for (int off = 32; off > 0; off >>= 1) ss += __shfl_down(ss, off);
  __shared__ float red[4];
  if ((t & 63) == 0) red[t >> 6] = ss;
  __syncthreads();
  const float tot = red[0] + red[1] + red[2] + red[3];
  const float sc = rsqrtf(tot * (1.0f / 1024.0f) + 1e-6f);
  const float4 gv = ((const float4*)g)[t];
  ushort4 o;
  o.x = f2b(v.x * sc * gv.x); o.y = f2b(v.y * sc * gv.y);
  o.z = f2b(v.z * sc * gv.z); o.w = f2b(v.w * sc * gv.w);
  *(ushort4*)(h + (size_t)row * 1024 + t * 4) = o;
}

// dst[c][r] = (bf16) src[r][c]
__global__ __launch_bounds__(256) void k_transpose_cast(const float* __restrict__ src,
                                                        int rows, int cols,
                                                        u16* __restrict__ dst) {
  __shared__ float tile[32][33];
  const int c0 = blockIdx.x * 32, r0 = blockIdx.y * 32;
  const int tx = threadIdx.x, ty = threadIdx.y;
  for (int i = 0; i < 32; i += 8)
    tile[ty + i][tx] = src[(size_t)(r0 + ty + i) * cols + c0 + tx];
  __syncthreads();
  for (int i = 0; i < 32; i += 8)
    dst[(size_t)(c0 + ty + i) * rows + r0 + tx] = f2b(tile[tx][ty + i]);
}

// vt[b][d][s] = v[(b*4096+s)*1024 + d]
__global__ __launch_bounds__(256) void k_vt(const u16* __restrict__ v, u16* __restrict__ vt) {
  __shared__ u16 tile[32][33];
  const int b = blockIdx.z;
  const int s0 = blockIdx.x * 32, d0 = blockIdx.y * 32;
  const int tx = threadIdx.x, ty = threadIdx.y;
  for (int i = 0; i < 32; i += 8)
    tile[ty + i][tx] = v[(size_t)(b * 4096 + s0 + ty + i) * 1024 + d0 + tx];
  __syncthreads();
  for (int i = 0; i < 32; i += 8)
    vt[(size_t)(b * 1024 + d0 + ty + i) * 4096 + s0 + tx] = tile[tx][ty + i];
}

// =======================================================================
// Shared MFMA GEMM core (m97 structure). PERM=1 applies qkv_permrow to B rows.
// =======================================================================
template <int PERM>
DEVI void gemm_tile(const u16* __restrict__ A, int lda,
                    const u16* __restrict__ B, int ldb,
                    int K, int m0, int n0,
                    u16* As, u16* Bs, f32x4 acc[4][4]) {
  const int t = threadIdx.x;
  const int sr = t >> 2;
  const int sc = (t & 3) * 8;
  int br0 = n0 + sr, br1 = n0 + 64 + sr;
  if (PERM) { br0 = qkv_permrow(br0); br1 = qkv_permrow(br1); }
  const u16* Ag0 = A + (size_t)(m0 + sr) * lda + sc;
  const u16* Ag1 = A + (size_t)(m0 + 64 + sr) * lda + sc;
  const u16* Bg0 = B + (size_t)br0 * ldb + sc;
  const u16* Bg1 = B + (size_t)br1 * ldb + sc;
  u16* Asw0 = As + t * 8;
  u16* Asw1 = As + 2048 + t * 8;
  u16* Bsw0 = Bs + t * 8;
  u16* Bsw1 = Bs + 2048 + t * 8;

  const int lane = t & 63, qd = lane >> 4, l16 = lane & 15;
  const int wave = t >> 6;
  const int wm = (wave >> 1) * 64, wn = (wave & 1) * 64;
  const u16* Ard = As + (size_t)(wm + l16) * 32 + qd * 8;
  const u16* Brd = Bs + (size_t)(wn + l16) * 32 + qd * 8;

  for (int k0 = 0; k0 < K; k0 += 32) {
    gld_lds16(Ag0 + k0, Asw0);
    gld_lds16(Ag1 + k0, Asw1);
    gld_lds16(Bg0 + k0, Bsw0);
    gld_lds16(Bg1 + k0, Bsw1);
    __builtin_amdgcn_s_waitcnt(0);
    __syncthreads();
    bf16x8 af[4], bfv[4];
#pragma unroll
    for (int i = 0; i < 4; i++) af[i] = *(const bf16x8*)(Ard + i * 16 * 32);
#pragma unroll
    for (int j = 0; j < 4; j++) bfv[j] = *(const bf16x8*)(Brd + j * 16 * 32);
#pragma unroll
    for (int i = 0; i < 4; i++)
#pragma unroll
      for (int j = 0; j < 4; j++)
        acc[i][j] = __builtin_amdgcn_mfma_f32_16x16x32_bf16(af[i], bfv[j], acc[i][j], 0, 0, 0);
    __syncthreads();
  }
}

#define GEMM_PROLOGUE()                                          \
  __shared__ alignas(16) u16 As[4096], Bs[4096];                 \
  f32x4 acc[4][4];                                               \
  _Pragma("unroll") for (int i = 0; i < 4; i++)                  \
      _Pragma("unroll") for (int j = 0; j < 4; j++)              \
          acc[i][j] = f32x4{0.f, 0.f, 0.f, 0.f};

#define GEMM_EPI_IDX()                                           \
  const int t = threadIdx.x, lane = t & 63, qd = lane >> 4,      \
            l16 = lane & 15, wave = t >> 6;                      \
  const int wm = (wave >> 1) * 64, wn = (wave & 1) * 64;         \
  (void)t;

// C/D layout: col = lane&15, row = quad*4 + reg

// qkv GEMM: permuted-B staging; epilogue applies ternary rope to q,k via
// shfl_xor(1) pair mixing, splits outputs into q, k, v buffers.
// XCD swizzle: m-stripe of 16 blocks per XCD (per-XCD L2 working set ~10 MB).
__global__ __launch_bounds__(256) void k_gemm_qkv(const u16* __restrict__ A, const u16* __restrict__ Bt,
                                                  const float* __restrict__ bias,
                                                  const short* __restrict__ cst,
                                                  u16* __restrict__ q, u16* __restrict__ k,
                                                  u16* __restrict__ v) {
  GEMM_PROLOGUE();
  const int bid = blockIdx.y * gridDim.x + blockIdx.x;
  const int xcd = bid & 7, idx = bid >> 3;
  const int m0 = (xcd * 16 + (idx & 15)) * 128;
  const int n0 = (idx >> 4) * 128;
  gemm_tile<1>(A, 1024, Bt, 1024, 1024, m0, n0, As, Bs, acc);
  GEMM_EPI_IDX();
  const int sec = n0 >> 10;          // 0=q 1=k 2=v (uniform per block)
  if (sec == 2) {
#pragma unroll
    for (int i = 0; i < 4; i++) {
      const int mb = m0 + wm + i * 16 + qd * 4;
#pragma unroll
      for (int j = 0; j < 4; j++) {
        const int col = n0 + wn + j * 16 + l16;         // physical (identity perm)
        const float bv = bias[col];
#pragma unroll
        for (int r = 0; r < 4; r++)
          v[(size_t)(mb + r) * 1024 + (col - 2048)] = f2b(acc[i][j][r] + bv);
      }
    }
  } else {
    u16* dst = (sec == 0) ? q : k;
#pragma unroll
    for (int i = 0; i < 4; i++) {
      const int mb = m0 + wm + i * 16 + qd * 4;
#pragma unroll
      for (int j = 0; j < 4; j++) {
        const int n = n0 + wn + j * 16 + l16;           // permuted col
        const int w = n & 1023;
        const int odd = w & 1;
        const int p = w >> 1;                           // rope pair index 0..511
        const int physw = odd ? p + 512 : p;
        const float bv = bias[(n & ~1023) | physw];
#pragma unroll
        for (int r = 0; r < 4; r++) {
          const int pos = (mb + r) & 4095;
          const short cspack = cst[(pos << 9) + p];
          const float c = (float)(signed char)(cspack & 0xff);
          const float s = (float)(signed char)(cspack >> 8);
          const float val = acc[i][j][r] + bv;
          const float partner = __shfl_xor(val, 1);
          const float outv = odd ? (val * c + partner * s) : (val * c - partner * s);
          dst[(size_t)(mb + r) * 1024 + physw] = f2b(outv);
        }
      }
    }
  }
}

// P = 3^(q k^T / 32) bf16, row sums ls via atomics. XCD 16m x 8n subgrid.
__global__ __launch_bounds__(256) void k_gemm_scores(const u16* __restrict__ q, const u16* __restrict__ kk,
                                                     u16* __restrict__ P, float* __restrict__ ls, int b0) {
  GEMM_PROLOGUE();
  const int zz = blockIdx.z, b = b0 + zz;
  const u16* A = q + (size_t)b * 4096 * 1024;
  const u16* Bt = kk + (size_t)b * 4096 * 1024;
  const int bid = blockIdx.y * 32 + blockIdx.x;
  const int xcd = bid & 7, idx = bid >> 3;
  const int m0 = ((xcd >> 2) * 16 + (idx & 15)) * 128;
  const int n0 = ((xcd & 3) * 8 + (idx >> 4)) * 128;
  gemm_tile<0>(A, 1024, Bt, 1024, 1024, m0, n0, As, Bs, acc);
  GEMM_EPI_IDX();
  const float C3 = 0.04953007814753613f;  // log2(3) / 32
  const size_t Pb = (size_t)zz * 4096 * 4096;
  f32x4 rowp[4];
#pragma unroll
  for (int i = 0; i < 4; i++) rowp[i] = f32x4{0.f, 0.f, 0.f, 0.f};
#pragma unroll
  for (int i = 0; i < 4; i++) {
    const int mb = m0 + wm + i * 16 + qd * 4;
#pragma unroll
    for (int j = 0; j < 4; j++) {
      const int col = n0 + wn + j * 16 + l16;
#pragma unroll
      for (int r = 0; r < 4; r++) {
        float pv = exp2f(acc[i][j][r] * C3);
        u16 pq = f2b(pv);
        P[Pb + (size_t)(mb + r) * 4096 + col] = pq;
        rowp[i][r] += b2f(pq);
      }
    }
  }
#pragma unroll
  for (int m = 1; m < 16; m <<= 1)
#pragma unroll
    for (int i = 0; i < 4; i++) {
      rowp[i].x += __shfl_xor(rowp[i].x, m);
      rowp[i].y += __shfl_xor(rowp[i].y, m);
      rowp[i].z += __shfl_xor(rowp[i].z, m);
      rowp[i].w += __shfl_xor(rowp[i].w, m);
    }
  if (l16 == 0) {
#pragma unroll
    for (int i = 0; i < 4; i++) {
      const int mb = m0 + wm + i * 16 + qd * 4;
#pragma unroll
      for (int r = 0; r < 4; r++)
        atomicAdd(ls + (size_t)b * 4096 + mb + r, rowp[i][r]);
    }
  }
}

// o = (P @ V) / ls. XCD 8m x 4n subgrid.
__global__ __launch_bounds__(256) void k_gemm_pv(const u16* __restrict__ P, const u16* __restrict__ vt,
                                                 const float* __restrict__ ls, u16* __restrict__ o, int b0) {
  GEMM_PROLOGUE();
  const int zz = blockIdx.z, b = b0 + zz;
  const u16* A = P + (size_t)zz * 4096 * 4096;
  const u16* Bt = vt + (size_t)b * 1024 * 4096;
  const int bid = blockIdx.y * 8 + blockIdx.x;
  const int xcd = bid & 7, idx = bid >> 3;
  const int m0 = ((xcd >> 1) * 8 + (idx & 7)) * 128;
  const int n0 = ((xcd & 1) * 4 + (idx >> 3)) * 128;
  gemm_tile<0>(A, 4096, Bt, 4096, 4096, m0, n0, As, Bs, acc);
  GEMM_EPI_IDX();
#pragma unroll
  for (int i = 0; i < 4; i++) {
    const int mb = m0 + wm + i * 16 + qd * 4;
    f32x4 inv;
#pragma unroll
    for (int r = 0; r < 4; r++) inv[r] = 1.0f / ls[(size_t)b * 4096 + mb + r];
#pragma unroll
    for (int j = 0; j < 4; j++) {
      const int col = n0 + wn + j * 16 + l16;
#pragma unroll
      for (int r = 0; r < 4; r++)
        o[(size_t)(b * 4096 + mb + r) * 1024 + col] = f2b(acc[i][j][r] * inv[r]);
    }
  }
}

// out = o @ WprojT^T + bias + x. XCD m-stripe of 16.
__global__ __launch_bounds__(256) void k_gemm_proj(const u16* __restrict__ A, const u16* __restrict__ Bt,
                                                   const float* __restrict__ bias, const float* __restrict__ x,
                                                   float* __restrict__ out) {
  GEMM_PROLOGUE();
  const int bid = blockIdx.y * gridDim.x + blockIdx.x;
  const int xcd = bid & 7, idx = bid >> 3;
  const int m0 = (xcd * 16 + (idx & 15)) * 128;
  const int n0 = (idx >> 4) * 128;
  gemm_tile<0>(A, 1024, Bt, 1024, 1024, m0, n0, As, Bs, acc);
  GEMM_EPI_IDX();
#pragma unroll
  for (int i = 0; i < 4; i++) {
    const int mb = m0 + wm + i * 16 + qd * 4;
#pragma unroll
    for (int j = 0; j < 4; j++) {
      const int col = n0 + wn + j * 16 + l16;
      const float bv = bias[col];
#pragma unroll
      for (int r = 0; r < 4; r++) {
        const size_t idxo = (size_t)(mb + r) * 1024 + col;
        out[idxo] = acc[i][j][r] + bv + x[idxo];
      }
    }
  }
}

// =======================================================================
extern "C" void kernel_launch(void* const* d_in, const int* in_sizes, int n_in,
                              void* d_out, int out_size, void* d_ws, size_t ws_size,
                              hipStream_t stream) {
  const float* x     = (const float*)d_in[0];
  const float* g     = (const float*)d_in[1];
  const float* wqkv  = (const float*)d_in[2];
  const float* bqkv  = (const float*)d_in[3];
  const float* wproj = (const float*)d_in[4];
  const float* bproj = (const float*)d_in[5];
  float* out = (float*)d_out;

  char* wsp = (char*)d_ws;
  size_t off = 0;
  auto take = [&](size_t bytes) -> void* {
    off = (off + 255) & ~(size_t)255;
    void* r = wsp + off;
    off += bytes;
    return r;
  };
  u16* h    = (u16*)take(16384ull * 1024 * 2);   // rmsnorm out; reused as o (PV out)
  u16* wqT  = (u16*)take(3072ull * 1024 * 2);
  u16* wpT  = (u16*)take(1024ull * 1024 * 2);
  u16* q    = (u16*)take(16384ull * 1024 * 2);
  u16* k    = (u16*)take(16384ull * 1024 * 2);
  u16* v    = (u16*)take(16384ull * 1024 * 2);
  u16* vt   = (u16*)take(4ull * 1024 * 4096 * 2);
  short* cst = (short*)take(4096ull * 512 * 2);
  float* ls = (float*)take(16384ull * 4);
  off = (off + 255) & ~(size_t)255;
  int nb = 4;
  while (nb > 1 && off + (size_t)nb * 4096 * 4096 * 2 > ws_size) nb >>= 1;
  u16* P = (u16*)(wsp + off);

  k_cs_table<<<8192, 256, 0, stream>>>(cst);
  k_transpose_cast<<<dim3(3072 / 32, 1024 / 32), dim3(32, 8), 0, stream>>>(wqkv, 1024, 3072, wqT);
  k_transpose_cast<<<dim3(1024 / 32, 1024 / 32), dim3(32, 8), 0, stream>>>(wproj, 1024, 1024, wpT);
  k_rmsnorm<<<16384, 256, 0, stream>>>(x, g, h);
  k_gemm_qkv<<<dim3(24, 128), 256, 0, stream>>>(h, wqT, bqkv, cst, q, k, v);
  k_vt<<<dim3(128, 32, 4), dim3(32, 8), 0, stream>>>(v, vt);
  hipMemsetAsync(ls, 0, 16384 * 4, stream);
  for (int b0 = 0; b0 < 4; b0 += nb) {
    k_gemm_scores<<<dim3(32, 32, nb), 256, 0, stream>>>(q, k, P, ls, b0);
    k_gemm_pv<<<dim3(8, 32, nb), 256, 0, stream>>>(P, vt, ls, h /*=o*/, b0);
  }
  k_gemm_proj<<<dim3(8, 128), 256, 0, stream>>>(h /*=o*/, wpT, bproj, x, out);
}